// Round 5
// baseline (183.397 us; speedup 1.0000x reference)
//
#include <hip/hip_runtime.h>
#include <math.h>

// ---------------------------------------------------------------------------
// M=30000 nodes, S=8 cells, D=32 channels, DEPTH_LIMIT=10, H=64, L=7M+1.
// ---------------------------------------------------------------------------

typedef __attribute__((ext_vector_type(8))) short short8;
typedef __attribute__((ext_vector_type(4))) float f32x4;

#define RCAP 30720   // per-depth run-list capacity (>= max possible runs)
#define WT_N 81920   // 10*32*32*8

// Kernel 0 (after a 40B memset of cnt): transpose conv_w [d][o][i][k] ->
// Wt [d][k][i][o]; zero feats; detect run starts of idx_sorted and emit
// depth-bucketed run list entries {t0 | n<<16 | cd<<24, p}.
__global__ __launch_bounds__(256) void prep_count(
    const float* __restrict__ conv_w, float* __restrict__ Wt,
    float* __restrict__ feats,
    const int* __restrict__ idx_sorted, const int* __restrict__ node_depth,
    int* __restrict__ cnt, int2* __restrict__ runlist, int M)
{
    int tid = blockIdx.x * 256 + threadIdx.x;
    if (tid < WT_N) {
        int o = tid & 31;
        int i = (tid >> 5) & 31;
        int k = (tid >> 10) & 7;
        int d = tid >> 13;
        Wt[tid] = conv_w[((d * 32 + o) * 32 + i) * 8 + k];
    } else if (tid < WT_N + 32) {
        feats[tid - WT_N] = 0.0f;
    } else {
        int t = tid - (WT_N + 32);
        if (t < M) {
            int p = idx_sorted[t] >> 3;
            bool start = (t == 0) || ((idx_sorted[t - 1] >> 3) != p);
            if (start) {
                int n = 1;
                while (t + n < M && (idx_sorted[t + n] >> 3) == p && n < 15) n++;
                int cd = node_depth[p];
                int pos = atomicAdd(&cnt[cd], 1);
                runlist[cd * RCAP + pos] = make_int2(t | (n << 16) | (cd << 24), p);
            }
        }
    }
}

__device__ __forceinline__ float4 shfl4(float4 v, int src) {
    float4 r;
    r.x = __shfl(v.x, src, 64);
    r.y = __shfl(v.y, src, 64);
    r.z = __shfl(v.z, src, 64);
    r.w = __shfl(v.w, src, 64);
    return r;
}

// 8-way register select (3-deep cndmask tree), avoids scratch from dynamic
// indexing (rule: runtime-indexed reg arrays spill).
__device__ __forceinline__ float4 sel8(const float4* b, int c) {
    float4 a0 = (c & 1) ? b[1] : b[0];
    float4 a1 = (c & 1) ? b[3] : b[2];
    float4 a2 = (c & 1) ? b[5] : b[4];
    float4 a3 = (c & 1) ? b[7] : b[6];
    float4 c0 = (c & 2) ? a1 : a0;
    float4 c1 = (c & 2) ? a3 : a2;
    return (c & 4) ? c1 : c0;
}

// Kernel 1: grid-strided waves over the depth-bucketed run list.
// Lane layout: og = (l&7)*4 -> 4 output channels; ig = l>>3 -> 4-channel
// input slice (i = ig*4..ig*4+3). All-register, no LDS, no barriers.
__global__ __launch_bounds__(256) void conv_scan(
    const float* __restrict__ data, const float* __restrict__ Wt,
    const float* __restrict__ conv_b, const float* __restrict__ depth_weight,
    const int* __restrict__ idx_sorted, const int* __restrict__ depth_sorted,
    const int* __restrict__ cnt, const int2* __restrict__ runlist,
    float* __restrict__ pfeats, float* __restrict__ patch,
    int M, int nwaves)
{
    int wid = (blockIdx.x * 256 + threadIdx.x) >> 6;
    int l   = threadIdx.x & 63;
    int og  = (l & 7) * 4;
    int ig  = l >> 3;
    int diag = ig * 9;           // source lane (ogg=ig, ig'=ig) for broadcasts

    for (int d = 0; d < 10; ++d) {
        int nd = cnt[d];
        const float* __restrict__ W = Wt + d * 8192;   // [k][i][o]
        for (int r = wid; r < nd; r += nwaves) {
            int2 e = runlist[d * RCAP + r];
            int t0 = e.x & 0xFFFF;
            int n  = (e.x >> 16) & 0xF;
            int p  = e.y;

            // preload per-step cell ids and depth weights (one coalesced pass)
            int   ec  = 0;
            float edw = 0.f;
            if (l < n) {
                ec  = idx_sorted[t0 + l] & 7;
                edw = depth_weight[depth_sorted[t0 + l]];
            }

            // blk rows in registers: lane holds rows k=0..7, channels og..og+3
            float4 blkreg[8];
            #pragma unroll
            for (int k = 0; k < 8; ++k)
                blkreg[k] = *(const float4*)(data + p * 256 + k * 32 + og);

            // full matvec: T[og..og+3] partial over i-slice ig
            float4 T = {0.f, 0.f, 0.f, 0.f};
            #pragma unroll
            for (int k = 0; k < 8; ++k) {
                float4 x4 = shfl4(blkreg[k], diag);
                const float4 w0 = *(const float4*)(W + (k * 32 + ig * 4 + 0) * 32 + og);
                const float4 w1 = *(const float4*)(W + (k * 32 + ig * 4 + 1) * 32 + og);
                const float4 w2 = *(const float4*)(W + (k * 32 + ig * 4 + 2) * 32 + og);
                const float4 w3 = *(const float4*)(W + (k * 32 + ig * 4 + 3) * 32 + og);
                T.x = fmaf(x4.x, w0.x, T.x); T.y = fmaf(x4.x, w0.y, T.y);
                T.z = fmaf(x4.x, w0.z, T.z); T.w = fmaf(x4.x, w0.w, T.w);
                T.x = fmaf(x4.y, w1.x, T.x); T.y = fmaf(x4.y, w1.y, T.y);
                T.z = fmaf(x4.y, w1.z, T.z); T.w = fmaf(x4.y, w1.w, T.w);
                T.x = fmaf(x4.z, w2.x, T.x); T.y = fmaf(x4.z, w2.y, T.y);
                T.z = fmaf(x4.z, w2.z, T.z); T.w = fmaf(x4.z, w2.w, T.w);
                T.x = fmaf(x4.w, w3.x, T.x); T.y = fmaf(x4.w, w3.y, T.y);
                T.z = fmaf(x4.w, w3.z, T.z); T.w = fmaf(x4.w, w3.w, T.w);
            }
            #pragma unroll
            for (int m = 8; m <= 32; m <<= 1) {
                T.x += __shfl_xor(T.x, m, 64);
                T.y += __shfl_xor(T.y, m, 64);
                T.z += __shfl_xor(T.z, m, 64);
                T.w += __shfl_xor(T.w, m, 64);
            }

            const float4 bias = *(const float4*)(conv_b + d * 32 + og);
            float4 pf = {0.f, 0.f, 0.f, 0.f};

            int c = __shfl(ec, 0, 64);
            float4 ov = sel8(blkreg, c);
            // W slice for step-0 incremental update
            float4 wc0 = *(const float4*)(W + (c * 32 + ig * 4 + 0) * 32 + og);
            float4 wc1 = *(const float4*)(W + (c * 32 + ig * 4 + 1) * 32 + og);
            float4 wc2 = *(const float4*)(W + (c * 32 + ig * 4 + 2) * 32 + og);
            float4 wc3 = *(const float4*)(W + (c * 32 + ig * 4 + 3) * 32 + og);

            for (int s = 0;; ++s) {
                float dw = __shfl(edw, s, 64);
                float4 feat = {T.x + bias.x, T.y + bias.y, T.z + bias.z, T.w + bias.w};
                pf.x = fmaf(dw, feat.x, pf.x); pf.y = fmaf(dw, feat.y, pf.y);
                pf.z = fmaf(dw, feat.z, pf.z); pf.w = fmaf(dw, feat.w, pf.w);

                if (s + 1 == n) {
                    if (p == 0 && c == 0 && ig == 0)
                        *(float4*)(patch + og) = feat;
                    break;
                }

                int cn = __shfl(ec, s + 1, 64);
                float4 ovn = sel8(blkreg, cn);
                // prefetch next step's W slice (off critical chain)
                float4 nw0 = *(const float4*)(W + (cn * 32 + ig * 4 + 0) * 32 + og);
                float4 nw1 = *(const float4*)(W + (cn * 32 + ig * 4 + 1) * 32 + og);
                float4 nw2 = *(const float4*)(W + (cn * 32 + ig * 4 + 2) * 32 + og);
                float4 nw3 = *(const float4*)(W + (cn * 32 + ig * 4 + 3) * 32 + og);

                float4 du = {feat.x - ov.x, feat.y - ov.y, feat.z - ov.z, feat.w - ov.w};
                float4 u  = shfl4(du, diag);

                float4 acc;
                acc.x = u.x * wc0.x; acc.y = u.x * wc0.y;
                acc.z = u.x * wc0.z; acc.w = u.x * wc0.w;
                acc.x = fmaf(u.y, wc1.x, acc.x); acc.y = fmaf(u.y, wc1.y, acc.y);
                acc.z = fmaf(u.y, wc1.z, acc.z); acc.w = fmaf(u.y, wc1.w, acc.w);
                acc.x = fmaf(u.z, wc2.x, acc.x); acc.y = fmaf(u.z, wc2.y, acc.y);
                acc.z = fmaf(u.z, wc2.z, acc.z); acc.w = fmaf(u.z, wc2.w, acc.w);
                acc.x = fmaf(u.w, wc3.x, acc.x); acc.y = fmaf(u.w, wc3.y, acc.y);
                acc.z = fmaf(u.w, wc3.z, acc.z); acc.w = fmaf(u.w, wc3.w, acc.w);
                #pragma unroll
                for (int m = 8; m <= 32; m <<= 1) {
                    acc.x += __shfl_xor(acc.x, m, 64);
                    acc.y += __shfl_xor(acc.y, m, 64);
                    acc.z += __shfl_xor(acc.z, m, 64);
                    acc.w += __shfl_xor(acc.w, m, 64);
                }
                T.x += acc.x; T.y += acc.y; T.z += acc.z; T.w += acc.w;

                // duplicate-adjacent (pack-0) case: next oldv is this feat
                ov = (cn == c) ? feat : ovn;
                c = cn;
                wc0 = nw0; wc1 = nw1; wc2 = nw2; wc3 = nw3;
            }

            if (ig == 0) *(float4*)(pfeats + t0 * 32 + og) = pf;
        }
    }
}

// Kernel 2: sum the per-run partial feats rows (valid only at run starts).
__global__ __launch_bounds__(1024) void reduce_feats(
    const int* __restrict__ idx_sorted, const float* __restrict__ pfeats,
    float* __restrict__ feats, int M)
{
    int ch  = threadIdx.x & 31;
    int sub = threadIdx.x >> 5;
    int base = blockIdx.x * 1000;
    int end  = base + 1000; if (end > M) end = M;

    float a = 0.f;
    for (int t = base + sub; t < end; t += 32) {
        int p = idx_sorted[t] >> 3;
        bool start = (t == 0) || ((idx_sorted[t - 1] >> 3) != p);
        if (start) a += pfeats[t * 32 + ch];
    }
    __shared__ float red[1024];
    red[sub * 32 + ch] = a;
    __syncthreads();
    #pragma unroll
    for (int h = 16; h > 0; h >>= 1) {
        if (sub < h) red[sub * 32 + ch] += red[(sub + h) * 32 + ch];
        __syncthreads();
    }
    if (sub == 0) atomicAdd(&feats[ch], red[ch]);
}

// bf16 round-to-nearest-even helpers for the hi/lo split.
__device__ __forceinline__ unsigned short f2bf_rne(float x) {
    union { float f; unsigned u; } v; v.f = x;
    unsigned r = v.u + 0x7FFFu + ((v.u >> 16) & 1u);
    return (unsigned short)(r >> 16);
}
__device__ __forceinline__ float bf2f(unsigned short h) {
    union { float f; unsigned u; } v; v.u = ((unsigned)h) << 16;
    return v.f;
}

// Inline erf-GELU (A&S 7.1.26, |erf err| <= 1.5e-7).
__device__ __forceinline__ float gelu_erf(float x)
{
    const float s  = x * 0.70710678118654752f;
    const float ax = fabsf(s);
    const float t  = __builtin_amdgcn_rcpf(fmaf(0.3275911f, ax, 1.0f));
    float poly = fmaf(1.061405429f, t, -1.453152027f);
    poly = fmaf(poly, t, 1.421413741f);
    poly = fmaf(poly, t, -0.284496736f);
    poly = fmaf(poly, t, 0.254829592f);
    poly *= t;
    const float e  = __expf(-s * s);
    float er = fmaf(-poly, e, 1.0f);
    er = copysignf(er, s);
    return 0.5f * x * (1.0f + er);
}

// Kernel 3: leaf gather + both MLPs via MFMA (unchanged from round 4).
__global__ __launch_bounds__(256) void mlp_kernel(
    const float* __restrict__ data, const float* __restrict__ feats,
    const float* __restrict__ patch, const int* __restrict__ leaf_idx,
    const float* __restrict__ hf_w1, const float* __restrict__ hf_b1,
    const float* __restrict__ hf_w2, const float* __restrict__ hf_b2,
    const float* __restrict__ hs_w1, const float* __restrict__ hs_b1,
    const float* __restrict__ hs_w2, const float* __restrict__ hs_b2,
    float* __restrict__ out, int L)
{
    int lane = threadIdx.x & 63;
    int base = blockIdx.x * 256 + (threadIdx.x >> 6) * 64;
    if (base >= L) return;
    int n0 = lane & 15;
    int kg = lane >> 4;
    int k0 = kg * 8;

    float fts[8];
    #pragma unroll
    for (int i = 0; i < 8; ++i) fts[i] = feats[k0 + i];

    short8 bhi[8], blo[8];
    #pragma unroll
    for (int m = 0; m < 2; ++m) {
        const float* __restrict__ w1 = m ? hs_w1 : hf_w1;
        #pragma unroll
        for (int t = 0; t < 4; ++t) {
            short8 h8, l8;
            #pragma unroll
            for (int i = 0; i < 8; ++i) {
                float w = w1[(k0 + i) * 64 + t * 16 + n0];
                unsigned short hh = f2bf_rne(w);
                h8[i] = (short)hh;
                l8[i] = (short)f2bf_rne(w - bf2f(hh));
            }
            bhi[m * 4 + t] = h8;
            blo[m * 4 + t] = l8;
        }
    }

    float w2r[16], b1r[8];
    #pragma unroll
    for (int t = 0; t < 4; ++t) {
        int h = t * 16 + n0;
        w2r[t * 4 + 0] = hf_w2[h * 3 + 0];
        w2r[t * 4 + 1] = hf_w2[h * 3 + 1];
        w2r[t * 4 + 2] = hf_w2[h * 3 + 2];
        w2r[t * 4 + 3] = hs_w2[h];
        b1r[t]     = hf_b1[h];
        b1r[4 + t] = hs_b1[h];
    }
    float b20 = hf_b2[0], b21 = hf_b2[1], b22 = hf_b2[2], b23 = hs_b2[0];

    #pragma unroll
    for (int tm = 0; tm < 4; ++tm) {
        int r  = base + tm * 16 + n0;
        int rc = r < L ? r : L - 1;
        int row = leaf_idx[rc];
        const float* __restrict__ src = (row == 0) ? patch : (data + (size_t)row * 32);
        short8 ahi, alo;
        #pragma unroll
        for (int i = 0; i < 8; ++i) {
            float x = src[k0 + i] + fts[i];
            unsigned short hh = f2bf_rne(x);
            ahi[i] = (short)hh;
            alo[i] = (short)f2bf_rne(x - bf2f(hh));
        }

        f32x4 acc[8];
        #pragma unroll
        for (int q = 0; q < 8; ++q) acc[q] = (f32x4){0.f, 0.f, 0.f, 0.f};
        #pragma unroll
        for (int q = 0; q < 8; ++q) {
            acc[q] = __builtin_amdgcn_mfma_f32_16x16x32_bf16(ahi, bhi[q], acc[q], 0, 0, 0);
            acc[q] = __builtin_amdgcn_mfma_f32_16x16x32_bf16(alo, bhi[q], acc[q], 0, 0, 0);
            acc[q] = __builtin_amdgcn_mfma_f32_16x16x32_bf16(ahi, blo[q], acc[q], 0, 0, 0);
        }

        float o[4][4];
        #pragma unroll
        for (int g2 = 0; g2 < 4; ++g2) {
            #pragma unroll
            for (int c = 0; c < 4; ++c) o[g2][c] = 0.f;
        }
        #pragma unroll
        for (int t = 0; t < 4; ++t) {
            #pragma unroll
            for (int reg = 0; reg < 4; ++reg) {
                float gf = gelu_erf(acc[t][reg] + b1r[t]);
                float gs = gelu_erf(acc[4 + t][reg] + b1r[4 + t]);
                o[reg][0] = fmaf(gf, w2r[t * 4 + 0], o[reg][0]);
                o[reg][1] = fmaf(gf, w2r[t * 4 + 1], o[reg][1]);
                o[reg][2] = fmaf(gf, w2r[t * 4 + 2], o[reg][2]);
                o[reg][3] = fmaf(gs, w2r[t * 4 + 3], o[reg][3]);
            }
        }
        #pragma unroll
        for (int mk = 1; mk < 16; mk <<= 1) {
            #pragma unroll
            for (int reg = 0; reg < 4; ++reg) {
                #pragma unroll
                for (int c = 0; c < 4; ++c)
                    o[reg][c] += __shfl_xor(o[reg][c], mk, 64);
            }
        }
        if (n0 < 4) {
            int rL = base + tm * 16 + kg * 4 + n0;
            if (rL < L) {
                float s0 = n0 == 0 ? o[0][0] : n0 == 1 ? o[1][0] : n0 == 2 ? o[2][0] : o[3][0];
                float s1 = n0 == 0 ? o[0][1] : n0 == 1 ? o[1][1] : n0 == 2 ? o[2][1] : o[3][1];
                float s2 = n0 == 0 ? o[0][2] : n0 == 1 ? o[1][2] : n0 == 2 ? o[2][2] : o[3][2];
                float s3 = n0 == 0 ? o[0][3] : n0 == 1 ? o[1][3] : n0 == 2 ? o[2][3] : o[3][3];
                float4 res = {s0 + b20, s1 + b21, s2 + b22, s3 + b23};
                *(float4*)(out + (size_t)rL * 4) = res;
            }
        }
    }
}

extern "C" void kernel_launch(void* const* d_in, const int* in_sizes, int n_in,
                              void* d_out, int out_size, void* d_ws, size_t ws_size,
                              hipStream_t stream)
{
    const float* data         = (const float*)d_in[0];
    const float* conv_w       = (const float*)d_in[1];
    const float* conv_b       = (const float*)d_in[2];
    const float* depth_weight = (const float*)d_in[3];
    const float* hf_w1        = (const float*)d_in[4];
    const float* hf_b1        = (const float*)d_in[5];
    const float* hf_w2        = (const float*)d_in[6];
    const float* hf_b2        = (const float*)d_in[7];
    const float* hs_w1        = (const float*)d_in[8];
    const float* hs_b1        = (const float*)d_in[9];
    const float* hs_w2        = (const float*)d_in[10];
    const float* hs_b2        = (const float*)d_in[11];
    const int*   idx_sorted   = (const int*)d_in[12];
    const int*   depth_sorted = (const int*)d_in[13];
    const int*   node_depth   = (const int*)d_in[14];
    const int*   leaf_idx     = (const int*)d_in[15];

    int M = in_sizes[12];   // 30000
    int L = in_sizes[15];   // 210001
    float* out = (float*)d_out;

    // ws layout (floats): Wt[81920] | feats[32] | patch[32] | pfeats[M*32]
    //                     | cnt[16 ints] | runlist[10*RCAP int2]
    float* Wt     = (float*)d_ws;
    float* feats  = Wt + WT_N;
    float* patch  = feats + 32;
    float* pfeats = patch + 32;
    int*   cnt    = (int*)(pfeats + (size_t)M * 32);
    int2*  runlist = (int2*)(cnt + 16);

    hipMemsetAsync(cnt, 0, 16 * sizeof(int), stream);

    int prep_total = WT_N + 32 + M;
    prep_count<<<(prep_total + 255) / 256, 256, 0, stream>>>(
        conv_w, Wt, feats, idx_sorted, node_depth, cnt, runlist, M);

    const int NBLK = 1024;                 // 4096 waves
    conv_scan<<<NBLK, 256, 0, stream>>>(data, Wt, conv_b, depth_weight,
                                        idx_sorted, depth_sorted, cnt, runlist,
                                        pfeats, patch, M, NBLK * 4);

    reduce_feats<<<(M + 999) / 1000, 1024, 0, stream>>>(idx_sorted, pfeats, feats, M);

    mlp_kernel<<<(L + 255) / 256, 256, 0, stream>>>(data, feats, patch, leaf_idx,
                                                    hf_w1, hf_b1, hf_w2, hf_b2,
                                                    hs_w1, hs_b1, hs_w2, hs_b2,
                                                    out, L);
}

// Round 6
// 116.582 us; speedup vs baseline: 1.5731x; 1.5731x over previous
//
#include <hip/hip_runtime.h>
#include <math.h>

// ---------------------------------------------------------------------------
// M=30000 nodes, S=8 cells, D=32 channels, DEPTH_LIMIT=10, H=64, L=7M+1.
// ---------------------------------------------------------------------------

typedef __attribute__((ext_vector_type(8))) short short8;
typedef __attribute__((ext_vector_type(4))) float f32x4;

#define WT_N 81920   // 10*32*32*8

// Kernel 0: transpose conv_w [d][o][i][k] -> Wt [d][k][i][o]; zero feats.
__global__ __launch_bounds__(256) void prep_kernel(
    const float* __restrict__ conv_w, float* __restrict__ Wt,
    float* __restrict__ feats)
{
    int tid = blockIdx.x * 256 + threadIdx.x;
    if (tid < WT_N) {
        int o = tid & 31;
        int i = (tid >> 5) & 31;
        int k = (tid >> 10) & 7;
        int d = tid >> 13;
        Wt[tid] = conv_w[((d * 32 + o) * 32 + i) * 8 + k];
    } else if (tid < WT_N + 32) {
        feats[tid - WT_N] = 0.0f;
    }
}

__device__ __forceinline__ float4 shfl4(float4 v, int src) {
    float4 r;
    r.x = __shfl(v.x, src, 64);
    r.y = __shfl(v.y, src, 64);
    r.z = __shfl(v.z, src, 64);
    r.w = __shfl(v.w, src, 64);
    return r;
}

// 8-way register select (3-deep cndmask tree) - no scratch from dyn indexing.
__device__ __forceinline__ float4 sel8(const float4* b, int c) {
    float4 a0 = (c & 1) ? b[1] : b[0];
    float4 a1 = (c & 1) ? b[3] : b[2];
    float4 a2 = (c & 1) ? b[5] : b[4];
    float4 a3 = (c & 1) ? b[7] : b[6];
    float4 c0 = (c & 2) ? a1 : a0;
    float4 c1 = (c & 2) ? a3 : a2;
    return (c & 4) ? c1 : c0;
}

// Kernel 1: grid-strided waves over t0; inline run detection (no atomics, no
// prebuilt list). Lanes 0-15 window-load idx_sorted[t0..t0+15]; run length by
// ballot (max run = 9). Heavy body: all-register incremental conv (round-5).
// Lane layout: og = (l&7)*4 output chans; ig = l>>3 input 4-slice.
__global__ __launch_bounds__(256) void conv_scan(
    const float* __restrict__ data, const float* __restrict__ Wt,
    const float* __restrict__ conv_b, const float* __restrict__ depth_weight,
    const int* __restrict__ idx_sorted, const int* __restrict__ depth_sorted,
    const int* __restrict__ node_depth,
    float* __restrict__ pfeats, float* __restrict__ patch,
    int M, int nwaves)
{
    int wid = (blockIdx.x * 256 + threadIdx.x) >> 6;
    int l   = threadIdx.x & 63;
    int og  = (l & 7) * 4;
    int ig  = l >> 3;
    int diag = ig * 9;           // lane holding (og-group ig, i-slice ig)

    for (int t0 = wid; t0 < M; t0 += nwaves) {
        // window load (coalesced 64B over lanes 0..15)
        int tl = t0 + (l & 15);
        int wv = idx_sorted[tl < M ? tl : M - 1];
        int p  = __builtin_amdgcn_readfirstlane(wv) >> 3;

        // run start? (wave-uniform scalar load)
        if (t0 > 0 && (idx_sorted[t0 - 1] >> 3) == p) continue;

        // run length via ballot over the window
        unsigned long long mask =
            __ballot((l < 16) && (tl < M) && ((wv >> 3) == p));
        int n = __builtin_ctzll(~mask);

        int cd = node_depth[p];
        const float* __restrict__ W = Wt + cd * 8192;   // [k][i][o]

        int   ec  = wv & 7;
        float edw = (l < n) ? depth_weight[depth_sorted[t0 + l]] : 0.f;

        // blk rows in registers: lane holds rows k=0..7, channels og..og+3
        float4 blkreg[8];
        #pragma unroll
        for (int k = 0; k < 8; ++k)
            blkreg[k] = *(const float4*)(data + p * 256 + k * 32 + og);

        // full matvec: T[og..og+3] partial over i-slice ig
        float4 T = {0.f, 0.f, 0.f, 0.f};
        #pragma unroll
        for (int k = 0; k < 8; ++k) {
            float4 x4 = shfl4(blkreg[k], diag);
            const float4 w0 = *(const float4*)(W + (k * 32 + ig * 4 + 0) * 32 + og);
            const float4 w1 = *(const float4*)(W + (k * 32 + ig * 4 + 1) * 32 + og);
            const float4 w2 = *(const float4*)(W + (k * 32 + ig * 4 + 2) * 32 + og);
            const float4 w3 = *(const float4*)(W + (k * 32 + ig * 4 + 3) * 32 + og);
            T.x = fmaf(x4.x, w0.x, T.x); T.y = fmaf(x4.x, w0.y, T.y);
            T.z = fmaf(x4.x, w0.z, T.z); T.w = fmaf(x4.x, w0.w, T.w);
            T.x = fmaf(x4.y, w1.x, T.x); T.y = fmaf(x4.y, w1.y, T.y);
            T.z = fmaf(x4.y, w1.z, T.z); T.w = fmaf(x4.y, w1.w, T.w);
            T.x = fmaf(x4.z, w2.x, T.x); T.y = fmaf(x4.z, w2.y, T.y);
            T.z = fmaf(x4.z, w2.z, T.z); T.w = fmaf(x4.z, w2.w, T.w);
            T.x = fmaf(x4.w, w3.x, T.x); T.y = fmaf(x4.w, w3.y, T.y);
            T.z = fmaf(x4.w, w3.z, T.z); T.w = fmaf(x4.w, w3.w, T.w);
        }
        #pragma unroll
        for (int m = 8; m <= 32; m <<= 1) {
            T.x += __shfl_xor(T.x, m, 64);
            T.y += __shfl_xor(T.y, m, 64);
            T.z += __shfl_xor(T.z, m, 64);
            T.w += __shfl_xor(T.w, m, 64);
        }

        const float4 bias = *(const float4*)(conv_b + cd * 32 + og);
        float4 pf = {0.f, 0.f, 0.f, 0.f};

        int c = __shfl(ec, 0, 64);
        float4 ov = sel8(blkreg, c);
        float4 wc0 = *(const float4*)(W + (c * 32 + ig * 4 + 0) * 32 + og);
        float4 wc1 = *(const float4*)(W + (c * 32 + ig * 4 + 1) * 32 + og);
        float4 wc2 = *(const float4*)(W + (c * 32 + ig * 4 + 2) * 32 + og);
        float4 wc3 = *(const float4*)(W + (c * 32 + ig * 4 + 3) * 32 + og);

        for (int s = 0;; ++s) {
            float dw = __shfl(edw, s, 64);
            float4 feat = {T.x + bias.x, T.y + bias.y, T.z + bias.z, T.w + bias.w};
            pf.x = fmaf(dw, feat.x, pf.x); pf.y = fmaf(dw, feat.y, pf.y);
            pf.z = fmaf(dw, feat.z, pf.z); pf.w = fmaf(dw, feat.w, pf.w);

            if (s + 1 == n) {
                if (p == 0 && c == 0 && ig == 0)
                    *(float4*)(patch + og) = feat;
                break;
            }

            int cn = __shfl(ec, s + 1, 64);
            float4 ovn = sel8(blkreg, cn);
            float4 nw0 = *(const float4*)(W + (cn * 32 + ig * 4 + 0) * 32 + og);
            float4 nw1 = *(const float4*)(W + (cn * 32 + ig * 4 + 1) * 32 + og);
            float4 nw2 = *(const float4*)(W + (cn * 32 + ig * 4 + 2) * 32 + og);
            float4 nw3 = *(const float4*)(W + (cn * 32 + ig * 4 + 3) * 32 + og);

            float4 du = {feat.x - ov.x, feat.y - ov.y, feat.z - ov.z, feat.w - ov.w};
            float4 u  = shfl4(du, diag);

            float4 acc;
            acc.x = u.x * wc0.x; acc.y = u.x * wc0.y;
            acc.z = u.x * wc0.z; acc.w = u.x * wc0.w;
            acc.x = fmaf(u.y, wc1.x, acc.x); acc.y = fmaf(u.y, wc1.y, acc.y);
            acc.z = fmaf(u.y, wc1.z, acc.z); acc.w = fmaf(u.y, wc1.w, acc.w);
            acc.x = fmaf(u.z, wc2.x, acc.x); acc.y = fmaf(u.z, wc2.y, acc.y);
            acc.z = fmaf(u.z, wc2.z, acc.z); acc.w = fmaf(u.z, wc2.w, acc.w);
            acc.x = fmaf(u.w, wc3.x, acc.x); acc.y = fmaf(u.w, wc3.y, acc.y);
            acc.z = fmaf(u.w, wc3.z, acc.z); acc.w = fmaf(u.w, wc3.w, acc.w);
            #pragma unroll
            for (int m = 8; m <= 32; m <<= 1) {
                acc.x += __shfl_xor(acc.x, m, 64);
                acc.y += __shfl_xor(acc.y, m, 64);
                acc.z += __shfl_xor(acc.z, m, 64);
                acc.w += __shfl_xor(acc.w, m, 64);
            }
            T.x += acc.x; T.y += acc.y; T.z += acc.z; T.w += acc.w;

            // duplicate-adjacent (pack 0 appears twice for p=0): oldv = feat
            ov = (cn == c) ? feat : ovn;
            c = cn;
            wc0 = nw0; wc1 = nw1; wc2 = nw2; wc3 = nw3;
        }

        if (ig == 0) *(float4*)(pfeats + t0 * 32 + og) = pf;
    }
}

// Kernel 2: sum the per-run partial feats rows (valid only at run starts).
__global__ __launch_bounds__(1024) void reduce_feats(
    const int* __restrict__ idx_sorted, const float* __restrict__ pfeats,
    float* __restrict__ feats, int M)
{
    int ch  = threadIdx.x & 31;
    int sub = threadIdx.x >> 5;
    int base = blockIdx.x * 1000;
    int end  = base + 1000; if (end > M) end = M;

    float a = 0.f;
    for (int t = base + sub; t < end; t += 32) {
        int p = idx_sorted[t] >> 3;
        bool start = (t == 0) || ((idx_sorted[t - 1] >> 3) != p);
        if (start) a += pfeats[t * 32 + ch];
    }
    __shared__ float red[1024];
    red[sub * 32 + ch] = a;
    __syncthreads();
    #pragma unroll
    for (int h = 16; h > 0; h >>= 1) {
        if (sub < h) red[sub * 32 + ch] += red[(sub + h) * 32 + ch];
        __syncthreads();
    }
    if (sub == 0) atomicAdd(&feats[ch], red[ch]);
}

// bf16 round-to-nearest-even helpers for the hi/lo split.
__device__ __forceinline__ unsigned short f2bf_rne(float x) {
    union { float f; unsigned u; } v; v.f = x;
    unsigned r = v.u + 0x7FFFu + ((v.u >> 16) & 1u);
    return (unsigned short)(r >> 16);
}
__device__ __forceinline__ float bf2f(unsigned short h) {
    union { float f; unsigned u; } v; v.u = ((unsigned)h) << 16;
    return v.f;
}

// Inline erf-GELU (A&S 7.1.26, |erf err| <= 1.5e-7).
__device__ __forceinline__ float gelu_erf(float x)
{
    const float s  = x * 0.70710678118654752f;
    const float ax = fabsf(s);
    const float t  = __builtin_amdgcn_rcpf(fmaf(0.3275911f, ax, 1.0f));
    float poly = fmaf(1.061405429f, t, -1.453152027f);
    poly = fmaf(poly, t, 1.421413741f);
    poly = fmaf(poly, t, -0.284496736f);
    poly = fmaf(poly, t, 0.254829592f);
    poly *= t;
    const float e  = __expf(-s * s);
    float er = fmaf(-poly, e, 1.0f);
    er = copysignf(er, s);
    return 0.5f * x * (1.0f + er);
}

// Kernel 3: leaf gather + both MLPs via MFMA (unchanged from round 4).
__global__ __launch_bounds__(256) void mlp_kernel(
    const float* __restrict__ data, const float* __restrict__ feats,
    const float* __restrict__ patch, const int* __restrict__ leaf_idx,
    const float* __restrict__ hf_w1, const float* __restrict__ hf_b1,
    const float* __restrict__ hf_w2, const float* __restrict__ hf_b2,
    const float* __restrict__ hs_w1, const float* __restrict__ hs_b1,
    const float* __restrict__ hs_w2, const float* __restrict__ hs_b2,
    float* __restrict__ out, int L)
{
    int lane = threadIdx.x & 63;
    int base = blockIdx.x * 256 + (threadIdx.x >> 6) * 64;
    if (base >= L) return;
    int n0 = lane & 15;
    int kg = lane >> 4;
    int k0 = kg * 8;

    float fts[8];
    #pragma unroll
    for (int i = 0; i < 8; ++i) fts[i] = feats[k0 + i];

    short8 bhi[8], blo[8];
    #pragma unroll
    for (int m = 0; m < 2; ++m) {
        const float* __restrict__ w1 = m ? hs_w1 : hf_w1;
        #pragma unroll
        for (int t = 0; t < 4; ++t) {
            short8 h8, l8;
            #pragma unroll
            for (int i = 0; i < 8; ++i) {
                float w = w1[(k0 + i) * 64 + t * 16 + n0];
                unsigned short hh = f2bf_rne(w);
                h8[i] = (short)hh;
                l8[i] = (short)f2bf_rne(w - bf2f(hh));
            }
            bhi[m * 4 + t] = h8;
            blo[m * 4 + t] = l8;
        }
    }

    float w2r[16], b1r[8];
    #pragma unroll
    for (int t = 0; t < 4; ++t) {
        int h = t * 16 + n0;
        w2r[t * 4 + 0] = hf_w2[h * 3 + 0];
        w2r[t * 4 + 1] = hf_w2[h * 3 + 1];
        w2r[t * 4 + 2] = hf_w2[h * 3 + 2];
        w2r[t * 4 + 3] = hs_w2[h];
        b1r[t]     = hf_b1[h];
        b1r[4 + t] = hs_b1[h];
    }
    float b20 = hf_b2[0], b21 = hf_b2[1], b22 = hf_b2[2], b23 = hs_b2[0];

    #pragma unroll
    for (int tm = 0; tm < 4; ++tm) {
        int r  = base + tm * 16 + n0;
        int rc = r < L ? r : L - 1;
        int row = leaf_idx[rc];
        const float* __restrict__ src = (row == 0) ? patch : (data + (size_t)row * 32);
        short8 ahi, alo;
        #pragma unroll
        for (int i = 0; i < 8; ++i) {
            float x = src[k0 + i] + fts[i];
            unsigned short hh = f2bf_rne(x);
            ahi[i] = (short)hh;
            alo[i] = (short)f2bf_rne(x - bf2f(hh));
        }

        f32x4 acc[8];
        #pragma unroll
        for (int q = 0; q < 8; ++q) acc[q] = (f32x4){0.f, 0.f, 0.f, 0.f};
        #pragma unroll
        for (int q = 0; q < 8; ++q) {
            acc[q] = __builtin_amdgcn_mfma_f32_16x16x32_bf16(ahi, bhi[q], acc[q], 0, 0, 0);
            acc[q] = __builtin_amdgcn_mfma_f32_16x16x32_bf16(alo, bhi[q], acc[q], 0, 0, 0);
            acc[q] = __builtin_amdgcn_mfma_f32_16x16x32_bf16(ahi, blo[q], acc[q], 0, 0, 0);
        }

        float o[4][4];
        #pragma unroll
        for (int g2 = 0; g2 < 4; ++g2) {
            #pragma unroll
            for (int c = 0; c < 4; ++c) o[g2][c] = 0.f;
        }
        #pragma unroll
        for (int t = 0; t < 4; ++t) {
            #pragma unroll
            for (int reg = 0; reg < 4; ++reg) {
                float gf = gelu_erf(acc[t][reg] + b1r[t]);
                float gs = gelu_erf(acc[4 + t][reg] + b1r[4 + t]);
                o[reg][0] = fmaf(gf, w2r[t * 4 + 0], o[reg][0]);
                o[reg][1] = fmaf(gf, w2r[t * 4 + 1], o[reg][1]);
                o[reg][2] = fmaf(gf, w2r[t * 4 + 2], o[reg][2]);
                o[reg][3] = fmaf(gs, w2r[t * 4 + 3], o[reg][3]);
            }
        }
        #pragma unroll
        for (int mk = 1; mk < 16; mk <<= 1) {
            #pragma unroll
            for (int reg = 0; reg < 4; ++reg) {
                #pragma unroll
                for (int c = 0; c < 4; ++c)
                    o[reg][c] += __shfl_xor(o[reg][c], mk, 64);
            }
        }
        if (n0 < 4) {
            int rL = base + tm * 16 + kg * 4 + n0;
            if (rL < L) {
                float s0 = n0 == 0 ? o[0][0] : n0 == 1 ? o[1][0] : n0 == 2 ? o[2][0] : o[3][0];
                float s1 = n0 == 0 ? o[0][1] : n0 == 1 ? o[1][1] : n0 == 2 ? o[2][1] : o[3][1];
                float s2 = n0 == 0 ? o[0][2] : n0 == 1 ? o[1][2] : n0 == 2 ? o[2][2] : o[3][2];
                float s3 = n0 == 0 ? o[0][3] : n0 == 1 ? o[1][3] : n0 == 2 ? o[2][3] : o[3][3];
                float4 res = {s0 + b20, s1 + b21, s2 + b22, s3 + b23};
                *(float4*)(out + (size_t)rL * 4) = res;
            }
        }
    }
}

extern "C" void kernel_launch(void* const* d_in, const int* in_sizes, int n_in,
                              void* d_out, int out_size, void* d_ws, size_t ws_size,
                              hipStream_t stream)
{
    const float* data         = (const float*)d_in[0];
    const float* conv_w       = (const float*)d_in[1];
    const float* conv_b       = (const float*)d_in[2];
    const float* depth_weight = (const float*)d_in[3];
    const float* hf_w1        = (const float*)d_in[4];
    const float* hf_b1        = (const float*)d_in[5];
    const float* hf_w2        = (const float*)d_in[6];
    const float* hf_b2        = (const float*)d_in[7];
    const float* hs_w1        = (const float*)d_in[8];
    const float* hs_b1        = (const float*)d_in[9];
    const float* hs_w2        = (const float*)d_in[10];
    const float* hs_b2        = (const float*)d_in[11];
    const int*   idx_sorted   = (const int*)d_in[12];
    const int*   depth_sorted = (const int*)d_in[13];
    const int*   node_depth   = (const int*)d_in[14];
    const int*   leaf_idx     = (const int*)d_in[15];

    int M = in_sizes[12];   // 30000
    int L = in_sizes[15];   // 210001
    float* out = (float*)d_out;

    // ws layout (floats): Wt[81920] | feats[32] | patch[32] | pfeats[M*32]
    float* Wt     = (float*)d_ws;
    float* feats  = Wt + WT_N;
    float* patch  = feats + 32;
    float* pfeats = patch + 32;

    prep_kernel<<<(WT_N + 32 + 255) / 256, 256, 0, stream>>>(conv_w, Wt, feats);

    const int NBLK = 1024;                 // 4096 waves
    conv_scan<<<NBLK, 256, 0, stream>>>(data, Wt, conv_b, depth_weight,
                                        idx_sorted, depth_sorted, node_depth,
                                        pfeats, patch, M, NBLK * 4);

    reduce_feats<<<(M + 999) / 1000, 1024, 0, stream>>>(idx_sorted, pfeats, feats, M);

    mlp_kernel<<<(L + 255) / 256, 256, 0, stream>>>(data, feats, patch, leaf_idx,
                                                    hf_w1, hf_b1, hf_w2, hf_b2,
                                                    hs_w1, hs_b1, hs_w2, hs_b2,
                                                    out, L);
}

// Round 7
// 88.823 us; speedup vs baseline: 2.0647x; 1.3125x over previous
//
#include <hip/hip_runtime.h>
#include <math.h>

// ---------------------------------------------------------------------------
// M=30000 nodes, S=8 cells, D=32 channels, DEPTH_LIMIT=10, H=64, L=7M+1.
// ---------------------------------------------------------------------------

typedef __attribute__((ext_vector_type(8))) short short8;
typedef __attribute__((ext_vector_type(4))) float f32x4;

#define WT_N 81920   // 10*32*32*8

// bf16 round-to-nearest-even helpers for the hi/lo split.
__device__ __forceinline__ unsigned short f2bf_rne(float x) {
    union { float f; unsigned u; } v; v.f = x;
    unsigned r = v.u + 0x7FFFu + ((v.u >> 16) & 1u);
    return (unsigned short)(r >> 16);
}
__device__ __forceinline__ float bf2f(unsigned short h) {
    union { float f; unsigned u; } v; v.u = ((unsigned)h) << 16;
    return v.f;
}

// Kernel 0: transpose conv_w [d][o][i][k] -> Wt [d][k][i][o]; zero feats;
// pre-convert both w1 matrices into packed bf16 hi/lo MFMA B-fragments.
// bpack fragment layout: q = mlp*4 + t (hidden tile), lane = kg*16+n0;
// element i = w1[(kg*8+i)*64 + t*16 + n0].
__global__ __launch_bounds__(256) void prep_kernel(
    const float* __restrict__ conv_w, float* __restrict__ Wt,
    float* __restrict__ feats,
    const float* __restrict__ hf_w1, const float* __restrict__ hs_w1,
    short* __restrict__ bph, short* __restrict__ bpl)
{
    int tid = blockIdx.x * 256 + threadIdx.x;
    if (tid < WT_N) {
        int o = tid & 31;
        int i = (tid >> 5) & 31;
        int k = (tid >> 10) & 7;
        int d = tid >> 13;
        Wt[tid] = conv_w[((d * 32 + o) * 32 + i) * 8 + k];
    } else if (tid < WT_N + 32) {
        feats[tid - WT_N] = 0.0f;
    } else if (tid < WT_N + 32 + 512) {
        int j = tid - (WT_N + 32);
        int lane = j & 63;
        int q = j >> 6;              // 0..7
        int m = q >> 2, tq = q & 3;
        int kg = lane >> 4, n0 = lane & 15, k0 = kg * 8;
        const float* __restrict__ w1 = m ? hs_w1 : hf_w1;
        #pragma unroll
        for (int i = 0; i < 8; ++i) {
            float w = w1[(k0 + i) * 64 + tq * 16 + n0];
            unsigned short hh = f2bf_rne(w);
            bph[(q * 64 + lane) * 8 + i] = (short)hh;
            bpl[(q * 64 + lane) * 8 + i] = (short)f2bf_rne(w - bf2f(hh));
        }
    }
}

__device__ __forceinline__ float4 shfl4(float4 v, int src) {
    float4 r;
    r.x = __shfl(v.x, src, 64);
    r.y = __shfl(v.y, src, 64);
    r.z = __shfl(v.z, src, 64);
    r.w = __shfl(v.w, src, 64);
    return r;
}

// Kernel 1: ONE WAVE PER CANDIDATE t0 (30000 waves). Non-starts exit after a
// single merged window load. Run body all-register, distributed block rows:
// lane (og8 = l&7, ig = l>>3) holds blk[row ig][chans og8*4..+3] (1 float4).
__global__ __launch_bounds__(256, 6) void conv_scan(
    const float* __restrict__ data, const float* __restrict__ Wt,
    const float* __restrict__ conv_b, const float* __restrict__ depth_weight,
    const int* __restrict__ idx_sorted, const int* __restrict__ depth_sorted,
    const int* __restrict__ node_depth,
    float* __restrict__ pfeats, float* __restrict__ patch, int M)
{
    int t0 = (blockIdx.x * 256 + threadIdx.x) >> 6;
    if (t0 >= M) return;
    int l   = threadIdx.x & 63;
    int og8 = l & 7;
    int og  = og8 * 4;
    int ig  = l >> 3;

    // merged window: pos wl holds idx_sorted[t0-1+wl] (wl=0 -> prev entry)
    int wl  = l & 15;
    int tw  = t0 - 1 + wl;
    int twc = tw < 0 ? 0 : (tw >= M ? M - 1 : tw);
    int iw  = idx_sorted[twc];
    int dsw = depth_sorted[twc];

    int p = __shfl(iw, 1, 64) >> 3;
    if (t0 > 0 && (__shfl(iw, 0, 64) >> 3) == p) return;   // not a run start

    unsigned long long mask =
        __ballot((l >= 1) && (l < 16) && (tw < M) && ((iw >> 3) == p));
    int n = __builtin_ctzll(~(mask >> 1));                  // run length (<=9)

    int   ec  = iw & 7;
    float edw = depth_weight[dsw & 15];

    int cd = node_depth[p];
    const float* __restrict__ W = Wt + cd * 8192;   // [k][i][o]

    // one block row per lane
    float4 blkrow = *(const float4*)(data + p * 256 + ig * 32 + og);

    // full matvec: lane accumulates T[og..og+3] over i-slice ig, all k
    float4 T = {0.f, 0.f, 0.f, 0.f};
    #pragma unroll
    for (int k = 0; k < 8; ++k) {
        float4 x4 = shfl4(blkrow, k * 8 + ig);   // blk[k][ig*4..ig*4+3]
        const float4 w0 = *(const float4*)(W + (k * 32 + ig * 4 + 0) * 32 + og);
        const float4 w1 = *(const float4*)(W + (k * 32 + ig * 4 + 1) * 32 + og);
        const float4 w2 = *(const float4*)(W + (k * 32 + ig * 4 + 2) * 32 + og);
        const float4 w3 = *(const float4*)(W + (k * 32 + ig * 4 + 3) * 32 + og);
        T.x = fmaf(x4.x, w0.x, T.x); T.y = fmaf(x4.x, w0.y, T.y);
        T.z = fmaf(x4.x, w0.z, T.z); T.w = fmaf(x4.x, w0.w, T.w);
        T.x = fmaf(x4.y, w1.x, T.x); T.y = fmaf(x4.y, w1.y, T.y);
        T.z = fmaf(x4.y, w1.z, T.z); T.w = fmaf(x4.y, w1.w, T.w);
        T.x = fmaf(x4.z, w2.x, T.x); T.y = fmaf(x4.z, w2.y, T.y);
        T.z = fmaf(x4.z, w2.z, T.z); T.w = fmaf(x4.z, w2.w, T.w);
        T.x = fmaf(x4.w, w3.x, T.x); T.y = fmaf(x4.w, w3.y, T.y);
        T.z = fmaf(x4.w, w3.z, T.z); T.w = fmaf(x4.w, w3.w, T.w);
    }
    #pragma unroll
    for (int m = 8; m <= 32; m <<= 1) {
        T.x += __shfl_xor(T.x, m, 64);
        T.y += __shfl_xor(T.y, m, 64);
        T.z += __shfl_xor(T.z, m, 64);
        T.w += __shfl_xor(T.w, m, 64);
    }

    const float4 bias = *(const float4*)(conv_b + cd * 32 + og);
    float4 pf = {0.f, 0.f, 0.f, 0.f};

    int c = __shfl(ec, 1, 64);
    float4 wc0 = *(const float4*)(W + (c * 32 + ig * 4 + 0) * 32 + og);
    float4 wc1 = *(const float4*)(W + (c * 32 + ig * 4 + 1) * 32 + og);
    float4 wc2 = *(const float4*)(W + (c * 32 + ig * 4 + 2) * 32 + og);
    float4 wc3 = *(const float4*)(W + (c * 32 + ig * 4 + 3) * 32 + og);

    for (int s = 0;; ++s) {
        float dw = __shfl(edw, s + 1, 64);
        float4 feat = {T.x + bias.x, T.y + bias.y, T.z + bias.z, T.w + bias.w};
        pf.x = fmaf(dw, feat.x, pf.x); pf.y = fmaf(dw, feat.y, pf.y);
        pf.z = fmaf(dw, feat.z, pf.z); pf.w = fmaf(dw, feat.w, pf.w);

        if (s + 1 == n) {
            // last step of the p==0 run has c==0: final flat row 0 (leaf patch)
            if (p == 0 && c == 0 && ig == 0)
                *(float4*)(patch + og) = feat;
            break;
        }

        int cn = __shfl(ec, s + 2, 64);
        float4 nw0 = *(const float4*)(W + (cn * 32 + ig * 4 + 0) * 32 + og);
        float4 nw1 = *(const float4*)(W + (cn * 32 + ig * 4 + 1) * 32 + og);
        float4 nw2 = *(const float4*)(W + (cn * 32 + ig * 4 + 2) * 32 + og);
        float4 nw3 = *(const float4*)(W + (cn * 32 + ig * 4 + 3) * 32 + og);

        // old value of row c (current, so adjacent-duplicate cells are handled)
        float4 ov = shfl4(blkrow, c * 8 + og8);
        float4 du = {feat.x - ov.x, feat.y - ov.y, feat.z - ov.z, feat.w - ov.w};
        if (ig == c) blkrow = feat;                 // scatter write into tree
        float4 u = shfl4(du, og8 * 8 + ig);         // delta at chans ig*4..+3

        float4 acc;
        acc.x = u.x * wc0.x; acc.y = u.x * wc0.y;
        acc.z = u.x * wc0.z; acc.w = u.x * wc0.w;
        acc.x = fmaf(u.y, wc1.x, acc.x); acc.y = fmaf(u.y, wc1.y, acc.y);
        acc.z = fmaf(u.y, wc1.z, acc.z); acc.w = fmaf(u.y, wc1.w, acc.w);
        acc.x = fmaf(u.z, wc2.x, acc.x); acc.y = fmaf(u.z, wc2.y, acc.y);
        acc.z = fmaf(u.z, wc2.z, acc.z); acc.w = fmaf(u.z, wc2.w, acc.w);
        acc.x = fmaf(u.w, wc3.x, acc.x); acc.y = fmaf(u.w, wc3.y, acc.y);
        acc.z = fmaf(u.w, wc3.z, acc.z); acc.w = fmaf(u.w, wc3.w, acc.w);
        #pragma unroll
        for (int m = 8; m <= 32; m <<= 1) {
            acc.x += __shfl_xor(acc.x, m, 64);
            acc.y += __shfl_xor(acc.y, m, 64);
            acc.z += __shfl_xor(acc.z, m, 64);
            acc.w += __shfl_xor(acc.w, m, 64);
        }
        T.x += acc.x; T.y += acc.y; T.z += acc.z; T.w += acc.w;

        c = cn;
        wc0 = nw0; wc1 = nw1; wc2 = nw2; wc3 = nw3;
    }

    if (ig == 0) *(float4*)(pfeats + t0 * 32 + og) = pf;
}

// Kernel 2: sum the per-run partial feats rows (valid only at run starts).
__global__ __launch_bounds__(1024) void reduce_feats(
    const int* __restrict__ idx_sorted, const float* __restrict__ pfeats,
    float* __restrict__ feats, int M)
{
    int ch  = threadIdx.x & 31;
    int sub = threadIdx.x >> 5;
    int base = blockIdx.x * 1000;
    int end  = base + 1000; if (end > M) end = M;

    float a = 0.f;
    for (int t = base + sub; t < end; t += 32) {
        int p = idx_sorted[t] >> 3;
        bool start = (t == 0) || ((idx_sorted[t - 1] >> 3) != p);
        if (start) a += pfeats[t * 32 + ch];
    }
    __shared__ float red[1024];
    red[sub * 32 + ch] = a;
    __syncthreads();
    #pragma unroll
    for (int h = 16; h > 0; h >>= 1) {
        if (sub < h) red[sub * 32 + ch] += red[(sub + h) * 32 + ch];
        __syncthreads();
    }
    if (sub == 0) atomicAdd(&feats[ch], red[ch]);
}

// Inline erf-GELU (A&S 7.1.26, |erf err| <= 1.5e-7).
__device__ __forceinline__ float gelu_erf(float x)
{
    const float s  = x * 0.70710678118654752f;
    const float ax = fabsf(s);
    const float t  = __builtin_amdgcn_rcpf(fmaf(0.3275911f, ax, 1.0f));
    float poly = fmaf(1.061405429f, t, -1.453152027f);
    poly = fmaf(poly, t, 1.421413741f);
    poly = fmaf(poly, t, -0.284496736f);
    poly = fmaf(poly, t, 0.254829592f);
    poly *= t;
    const float e  = __expf(-s * s);
    float er = fmaf(-poly, e, 1.0f);
    er = copysignf(er, s);
    return 0.5f * x * (1.0f + er);
}

// Kernel 3: leaf gather + both MLPs via MFMA. B-fragments pre-packed by prep.
__global__ __launch_bounds__(256, 4) void mlp_kernel(
    const float* __restrict__ data, const float* __restrict__ feats,
    const float* __restrict__ patch, const int* __restrict__ leaf_idx,
    const short* __restrict__ bph, const short* __restrict__ bpl,
    const float* __restrict__ hf_b1, const float* __restrict__ hf_w2,
    const float* __restrict__ hf_b2,
    const float* __restrict__ hs_b1, const float* __restrict__ hs_w2,
    const float* __restrict__ hs_b2,
    float* __restrict__ out, int L)
{
    int lane = threadIdx.x & 63;
    int base = blockIdx.x * 256 + (threadIdx.x >> 6) * 64;
    if (base >= L) return;
    int n0 = lane & 15;
    int kg = lane >> 4;
    int k0 = kg * 8;

    float fts[8];
    #pragma unroll
    for (int i = 0; i < 8; ++i) fts[i] = feats[k0 + i];

    float w2r[16], b1r[8];
    #pragma unroll
    for (int t = 0; t < 4; ++t) {
        int h = t * 16 + n0;
        w2r[t * 4 + 0] = hf_w2[h * 3 + 0];
        w2r[t * 4 + 1] = hf_w2[h * 3 + 1];
        w2r[t * 4 + 2] = hf_w2[h * 3 + 2];
        w2r[t * 4 + 3] = hs_w2[h];
        b1r[t]     = hf_b1[h];
        b1r[4 + t] = hs_b1[h];
    }
    float b20 = hf_b2[0], b21 = hf_b2[1], b22 = hf_b2[2], b23 = hs_b2[0];

    #pragma unroll
    for (int tm = 0; tm < 4; ++tm) {
        int r  = base + tm * 16 + n0;
        int rc = r < L ? r : L - 1;
        int row = leaf_idx[rc];
        const float* __restrict__ src = (row == 0) ? patch : (data + (size_t)row * 32);
        float4 v0 = *(const float4*)(src + k0);
        float4 v1 = *(const float4*)(src + k0 + 4);
        float xv[8] = {v0.x, v0.y, v0.z, v0.w, v1.x, v1.y, v1.z, v1.w};
        short8 ahi, alo;
        #pragma unroll
        for (int i = 0; i < 8; ++i) {
            float x = xv[i] + fts[i];
            unsigned short hh = f2bf_rne(x);
            ahi[i] = (short)hh;
            alo[i] = (short)f2bf_rne(x - bf2f(hh));
        }

        f32x4 acc[8];
        #pragma unroll
        for (int q = 0; q < 8; ++q) {
            short8 bh = *(const short8*)(bph + (q * 64 + lane) * 8);
            short8 bl = *(const short8*)(bpl + (q * 64 + lane) * 8);
            f32x4 a = (f32x4){0.f, 0.f, 0.f, 0.f};
            a = __builtin_amdgcn_mfma_f32_16x16x32_bf16(ahi, bh, a, 0, 0, 0);
            a = __builtin_amdgcn_mfma_f32_16x16x32_bf16(alo, bh, a, 0, 0, 0);
            a = __builtin_amdgcn_mfma_f32_16x16x32_bf16(ahi, bl, a, 0, 0, 0);
            acc[q] = a;
        }

        float o[4][4];
        #pragma unroll
        for (int g2 = 0; g2 < 4; ++g2) {
            #pragma unroll
            for (int c = 0; c < 4; ++c) o[g2][c] = 0.f;
        }
        #pragma unroll
        for (int t = 0; t < 4; ++t) {
            #pragma unroll
            for (int reg = 0; reg < 4; ++reg) {
                float gf = gelu_erf(acc[t][reg] + b1r[t]);
                float gs = gelu_erf(acc[4 + t][reg] + b1r[4 + t]);
                o[reg][0] = fmaf(gf, w2r[t * 4 + 0], o[reg][0]);
                o[reg][1] = fmaf(gf, w2r[t * 4 + 1], o[reg][1]);
                o[reg][2] = fmaf(gf, w2r[t * 4 + 2], o[reg][2]);
                o[reg][3] = fmaf(gs, w2r[t * 4 + 3], o[reg][3]);
            }
        }
        #pragma unroll
        for (int mk = 1; mk < 16; mk <<= 1) {
            #pragma unroll
            for (int reg = 0; reg < 4; ++reg) {
                #pragma unroll
                for (int c = 0; c < 4; ++c)
                    o[reg][c] += __shfl_xor(o[reg][c], mk, 64);
            }
        }
        if (n0 < 4) {
            int rL = base + tm * 16 + kg * 4 + n0;
            if (rL < L) {
                float s0 = n0 == 0 ? o[0][0] : n0 == 1 ? o[1][0] : n0 == 2 ? o[2][0] : o[3][0];
                float s1 = n0 == 0 ? o[0][1] : n0 == 1 ? o[1][1] : n0 == 2 ? o[2][1] : o[3][1];
                float s2 = n0 == 0 ? o[0][2] : n0 == 1 ? o[1][2] : n0 == 2 ? o[2][2] : o[3][2];
                float s3 = n0 == 0 ? o[0][3] : n0 == 1 ? o[1][3] : n0 == 2 ? o[2][3] : o[3][3];
                float4 res = {s0 + b20, s1 + b21, s2 + b22, s3 + b23};
                *(float4*)(out + (size_t)rL * 4) = res;
            }
        }
    }
}

extern "C" void kernel_launch(void* const* d_in, const int* in_sizes, int n_in,
                              void* d_out, int out_size, void* d_ws, size_t ws_size,
                              hipStream_t stream)
{
    const float* data         = (const float*)d_in[0];
    const float* conv_w       = (const float*)d_in[1];
    const float* conv_b       = (const float*)d_in[2];
    const float* depth_weight = (const float*)d_in[3];
    const float* hf_w1        = (const float*)d_in[4];
    const float* hf_b1        = (const float*)d_in[5];
    const float* hf_w2        = (const float*)d_in[6];
    const float* hf_b2        = (const float*)d_in[7];
    const float* hs_w1        = (const float*)d_in[8];
    const float* hs_b1        = (const float*)d_in[9];
    const float* hs_w2        = (const float*)d_in[10];
    const float* hs_b2        = (const float*)d_in[11];
    const int*   idx_sorted   = (const int*)d_in[12];
    const int*   depth_sorted = (const int*)d_in[13];
    const int*   node_depth   = (const int*)d_in[14];
    const int*   leaf_idx     = (const int*)d_in[15];

    int M = in_sizes[12];   // 30000
    int L = in_sizes[15];   // 210001
    float* out = (float*)d_out;

    // ws layout (floats): Wt[81920] | feats[32] | patch[32] | pfeats[M*32]
    //                     | bph[4096 shorts] | bpl[4096 shorts]
    float* Wt     = (float*)d_ws;
    float* feats  = Wt + WT_N;
    float* patch  = feats + 32;
    float* pfeats = patch + 32;
    short* bph    = (short*)(pfeats + (size_t)M * 32);
    short* bpl    = bph + 4096;

    prep_kernel<<<(WT_N + 32 + 512 + 255) / 256, 256, 0, stream>>>(
        conv_w, Wt, feats, hf_w1, hs_w1, bph, bpl);

    conv_scan<<<(M + 3) / 4, 256, 0, stream>>>(data, Wt, conv_b, depth_weight,
                                               idx_sorted, depth_sorted, node_depth,
                                               pfeats, patch, M);

    reduce_feats<<<(M + 999) / 1000, 1024, 0, stream>>>(idx_sorted, pfeats, feats, M);

    mlp_kernel<<<(L + 255) / 256, 256, 0, stream>>>(data, feats, patch, leaf_idx,
                                                    bph, bpl,
                                                    hf_b1, hf_w2, hf_b2,
                                                    hs_b1, hs_w2, hs_b2,
                                                    out, L);
}

// Round 8
// 85.000 us; speedup vs baseline: 2.1576x; 1.0450x over previous
//
#include <hip/hip_runtime.h>
#include <math.h>

// ---------------------------------------------------------------------------
// M=30000 nodes, S=8 cells, D=32 channels, DEPTH_LIMIT=10, H=64, L=7M+1.
// ---------------------------------------------------------------------------

typedef __attribute__((ext_vector_type(8))) short short8;
typedef __attribute__((ext_vector_type(4))) float f32x4;

#define WT_N 81920    // 10*32*32*8
#define RCAP 30720    // per-depth run-list capacity
#define RSTRIDE 32    // gcnt padding (ints) -> one counter per 128B line

// bf16 round-to-nearest-even helpers for the hi/lo split.
__device__ __forceinline__ unsigned short f2bf_rne(float x) {
    union { float f; unsigned u; } v; v.f = x;
    unsigned r = v.u + 0x7FFFu + ((v.u >> 16) & 1u);
    return (unsigned short)(r >> 16);
}
__device__ __forceinline__ float bf2f(unsigned short h) {
    union { float f; unsigned u; } v; v.u = ((unsigned)h) << 16;
    return v.f;
}

// Kernel 0: run detection + depth-bucketed scatter (LDS histogram, one
// padded-line global atomic per block*depth), W transpose, feats zero,
// w1 bf16 hi/lo fragment packing. gcnt must be zeroed beforehand.
__global__ __launch_bounds__(256) void prep_kernel(
    const float* __restrict__ conv_w, float* __restrict__ Wt,
    float* __restrict__ feats,
    const float* __restrict__ hf_w1, const float* __restrict__ hs_w1,
    short* __restrict__ bph, short* __restrict__ bpl,
    const int* __restrict__ idx_sorted, const int* __restrict__ node_depth,
    int* __restrict__ gcnt, int2* __restrict__ runlist, int M)
{
    __shared__ int hcnt[16], hbase[16];
    if (threadIdx.x < 16) hcnt[threadIdx.x] = 0;
    __syncthreads();

    int tid = blockIdx.x * 256 + threadIdx.x;
    bool start = false;
    int d = 0, myp = 0, mypos = 0;

    if (tid < M) {
        int t = tid;
        int p = idx_sorted[t] >> 3;
        start = (t == 0) || ((idx_sorted[t - 1] >> 3) != p);
        if (start) {
            d = node_depth[p];
            myp = p;
            mypos = atomicAdd(&hcnt[d], 1);   // LDS atomic
        }
    } else if (tid < M + WT_N) {
        int j = tid - M;
        int o = j & 31;
        int i = (j >> 5) & 31;
        int k = (j >> 10) & 7;
        int dd = j >> 13;
        Wt[j] = conv_w[((dd * 32 + o) * 32 + i) * 8 + k];
    } else if (tid < M + WT_N + 32) {
        feats[tid - M - WT_N] = 0.0f;
    } else if (tid < M + WT_N + 32 + 512) {
        int j = tid - (M + WT_N + 32);
        int lane = j & 63;
        int q = j >> 6;              // 0..7 = mlp*4 + hidden-tile
        int m = q >> 2, tq = q & 3;
        int kg = lane >> 4, n0 = lane & 15, k0 = kg * 8;
        const float* __restrict__ w1 = m ? hs_w1 : hf_w1;
        #pragma unroll
        for (int i = 0; i < 8; ++i) {
            float w = w1[(k0 + i) * 64 + tq * 16 + n0];
            unsigned short hh = f2bf_rne(w);
            bph[(q * 64 + lane) * 8 + i] = (short)hh;
            bpl[(q * 64 + lane) * 8 + i] = (short)f2bf_rne(w - bf2f(hh));
        }
    }

    __syncthreads();
    if (threadIdx.x < 16) {
        int c = hcnt[threadIdx.x];
        if (c > 0) hbase[threadIdx.x] = atomicAdd(&gcnt[threadIdx.x * RSTRIDE], c);
    }
    __syncthreads();
    if (start) runlist[d * RCAP + hbase[d] + mypos] = make_int2(tid, myp);
}

__device__ __forceinline__ float4 shfl4(float4 v, int src) {
    float4 r;
    r.x = __shfl(v.x, src, 64);
    r.y = __shfl(v.y, src, 64);
    r.z = __shfl(v.z, src, 64);
    r.w = __shfl(v.w, src, 64);
    return r;
}

// Kernel 1: one wave per run-list entry, entries dense and depth-sorted ->
// consecutive waves share the same W (L1/L2-hot), no wasted waves, no
// node_depth load. Body: all-register incremental conv (round-7).
// Lane layout: og8 = l&7 (4 out-chans), ig = l>>3 (block row / i-slice).
__global__ __launch_bounds__(256, 6) void conv_scan(
    const float* __restrict__ data, const float* __restrict__ Wt,
    const float* __restrict__ conv_b, const float* __restrict__ depth_weight,
    const int* __restrict__ idx_sorted, const int* __restrict__ depth_sorted,
    const int* __restrict__ gcnt, const int2* __restrict__ runlist,
    float* __restrict__ pfeats, float* __restrict__ patch, int M)
{
    int r = (blockIdx.x * 256 + threadIdx.x) >> 6;
    int l   = threadIdx.x & 63;
    int og8 = l & 7;
    int og  = og8 * 4;
    int ig  = l >> 3;

    // rank -> (depth bucket, position): unrolled compare chain, no dyn index
    int acc = 0, cd = -1, pos = 0;
    #pragma unroll
    for (int d = 0; d < 10; ++d) {
        int c = gcnt[d * RSTRIDE];
        if (cd < 0 && r < acc + c) { cd = d; pos = r - acc; }
        acc += c;
    }
    if (cd < 0) return;

    int2 e = runlist[cd * RCAP + pos];
    int t0 = e.x, p = e.y;

    // window: lanes 0..15 hold idx/depth_sorted[t0+wl]
    int wl  = l & 15;
    int tw  = t0 + wl;
    int twc = tw < M ? tw : M - 1;
    int iw  = idx_sorted[twc];
    int dsw = depth_sorted[twc];

    unsigned long long mask =
        __ballot((l < 16) && (tw < M) && ((iw >> 3) == p));
    int n = __builtin_ctzll(~mask);                 // run length (<=9)

    int   ec  = iw & 7;
    float edw = depth_weight[dsw & 15];

    const float* __restrict__ W = Wt + cd * 8192;   // [k][i][o]

    // one block row per lane: blk[row ig][chans og..og+3]
    float4 blkrow = *(const float4*)(data + p * 256 + ig * 32 + og);

    // full matvec: lane accumulates T[og..og+3] over i-slice ig, all k
    float4 T = {0.f, 0.f, 0.f, 0.f};
    #pragma unroll
    for (int k = 0; k < 8; ++k) {
        float4 x4 = shfl4(blkrow, k * 8 + ig);      // blk[k][ig*4..ig*4+3]
        const float4 w0 = *(const float4*)(W + (k * 32 + ig * 4 + 0) * 32 + og);
        const float4 w1 = *(const float4*)(W + (k * 32 + ig * 4 + 1) * 32 + og);
        const float4 w2 = *(const float4*)(W + (k * 32 + ig * 4 + 2) * 32 + og);
        const float4 w3 = *(const float4*)(W + (k * 32 + ig * 4 + 3) * 32 + og);
        T.x = fmaf(x4.x, w0.x, T.x); T.y = fmaf(x4.x, w0.y, T.y);
        T.z = fmaf(x4.x, w0.z, T.z); T.w = fmaf(x4.x, w0.w, T.w);
        T.x = fmaf(x4.y, w1.x, T.x); T.y = fmaf(x4.y, w1.y, T.y);
        T.z = fmaf(x4.y, w1.z, T.z); T.w = fmaf(x4.y, w1.w, T.w);
        T.x = fmaf(x4.z, w2.x, T.x); T.y = fmaf(x4.z, w2.y, T.y);
        T.z = fmaf(x4.z, w2.z, T.z); T.w = fmaf(x4.z, w2.w, T.w);
        T.x = fmaf(x4.w, w3.x, T.x); T.y = fmaf(x4.w, w3.y, T.y);
        T.z = fmaf(x4.w, w3.z, T.z); T.w = fmaf(x4.w, w3.w, T.w);
    }
    #pragma unroll
    for (int m = 8; m <= 32; m <<= 1) {
        T.x += __shfl_xor(T.x, m, 64);
        T.y += __shfl_xor(T.y, m, 64);
        T.z += __shfl_xor(T.z, m, 64);
        T.w += __shfl_xor(T.w, m, 64);
    }

    const float4 bias = *(const float4*)(conv_b + cd * 32 + og);
    float4 pf = {0.f, 0.f, 0.f, 0.f};

    int c = __shfl(ec, 0, 64);
    float4 wc0 = *(const float4*)(W + (c * 32 + ig * 4 + 0) * 32 + og);
    float4 wc1 = *(const float4*)(W + (c * 32 + ig * 4 + 1) * 32 + og);
    float4 wc2 = *(const float4*)(W + (c * 32 + ig * 4 + 2) * 32 + og);
    float4 wc3 = *(const float4*)(W + (c * 32 + ig * 4 + 3) * 32 + og);

    for (int s = 0;; ++s) {
        float dw = __shfl(edw, s, 64);
        float4 feat = {T.x + bias.x, T.y + bias.y, T.z + bias.z, T.w + bias.w};
        pf.x = fmaf(dw, feat.x, pf.x); pf.y = fmaf(dw, feat.y, pf.y);
        pf.z = fmaf(dw, feat.z, pf.z); pf.w = fmaf(dw, feat.w, pf.w);

        if (s + 1 == n) {
            // last step of the p==0 run has c==0: final flat row 0 (leaf patch)
            if (p == 0 && c == 0 && ig == 0)
                *(float4*)(patch + og) = feat;
            break;
        }

        int cn = __shfl(ec, s + 1, 64);
        float4 nw0 = *(const float4*)(W + (cn * 32 + ig * 4 + 0) * 32 + og);
        float4 nw1 = *(const float4*)(W + (cn * 32 + ig * 4 + 1) * 32 + og);
        float4 nw2 = *(const float4*)(W + (cn * 32 + ig * 4 + 2) * 32 + og);
        float4 nw3 = *(const float4*)(W + (cn * 32 + ig * 4 + 3) * 32 + og);

        // old value of row c from CURRENT state (handles duplicate cells)
        float4 ov = shfl4(blkrow, c * 8 + og8);
        float4 du = {feat.x - ov.x, feat.y - ov.y, feat.z - ov.z, feat.w - ov.w};
        if (ig == c) blkrow = feat;                 // scatter write into tree
        float4 u = shfl4(du, og8 * 8 + ig);         // delta at chans ig*4..+3

        float4 acc4;
        acc4.x = u.x * wc0.x; acc4.y = u.x * wc0.y;
        acc4.z = u.x * wc0.z; acc4.w = u.x * wc0.w;
        acc4.x = fmaf(u.y, wc1.x, acc4.x); acc4.y = fmaf(u.y, wc1.y, acc4.y);
        acc4.z = fmaf(u.y, wc1.z, acc4.z); acc4.w = fmaf(u.y, wc1.w, acc4.w);
        acc4.x = fmaf(u.z, wc2.x, acc4.x); acc4.y = fmaf(u.z, wc2.y, acc4.y);
        acc4.z = fmaf(u.z, wc2.z, acc4.z); acc4.w = fmaf(u.z, wc2.w, acc4.w);
        acc4.x = fmaf(u.w, wc3.x, acc4.x); acc4.y = fmaf(u.w, wc3.y, acc4.y);
        acc4.z = fmaf(u.w, wc3.z, acc4.z); acc4.w = fmaf(u.w, wc3.w, acc4.w);
        #pragma unroll
        for (int m = 8; m <= 32; m <<= 1) {
            acc4.x += __shfl_xor(acc4.x, m, 64);
            acc4.y += __shfl_xor(acc4.y, m, 64);
            acc4.z += __shfl_xor(acc4.z, m, 64);
            acc4.w += __shfl_xor(acc4.w, m, 64);
        }
        T.x += acc4.x; T.y += acc4.y; T.z += acc4.z; T.w += acc4.w;

        c = cn;
        wc0 = nw0; wc1 = nw1; wc2 = nw2; wc3 = nw3;
    }

    if (ig == 0) *(float4*)(pfeats + t0 * 32 + og) = pf;
}

// Kernel 2: sum the per-run partial feats rows (valid only at run starts).
__global__ __launch_bounds__(1024) void reduce_feats(
    const int* __restrict__ idx_sorted, const float* __restrict__ pfeats,
    float* __restrict__ feats, int M)
{
    int ch  = threadIdx.x & 31;
    int sub = threadIdx.x >> 5;
    int base = blockIdx.x * 1000;
    int end  = base + 1000; if (end > M) end = M;

    float a = 0.f;
    for (int t = base + sub; t < end; t += 32) {
        int p = idx_sorted[t] >> 3;
        bool start = (t == 0) || ((idx_sorted[t - 1] >> 3) != p);
        if (start) a += pfeats[t * 32 + ch];
    }
    __shared__ float red[1024];
    red[sub * 32 + ch] = a;
    __syncthreads();
    #pragma unroll
    for (int h = 16; h > 0; h >>= 1) {
        if (sub < h) red[sub * 32 + ch] += red[(sub + h) * 32 + ch];
        __syncthreads();
    }
    if (sub == 0) atomicAdd(&feats[ch], red[ch]);
}

// Inline erf-GELU (A&S 7.1.26, |erf err| <= 1.5e-7).
__device__ __forceinline__ float gelu_erf(float x)
{
    const float s  = x * 0.70710678118654752f;
    const float ax = fabsf(s);
    const float t  = __builtin_amdgcn_rcpf(fmaf(0.3275911f, ax, 1.0f));
    float poly = fmaf(1.061405429f, t, -1.453152027f);
    poly = fmaf(poly, t, 1.421413741f);
    poly = fmaf(poly, t, -0.284496736f);
    poly = fmaf(poly, t, 0.254829592f);
    poly *= t;
    const float e  = __expf(-s * s);
    float er = fmaf(-poly, e, 1.0f);
    er = copysignf(er, s);
    return 0.5f * x * (1.0f + er);
}

// Kernel 3: leaf gather + both MLPs via MFMA (unchanged from round 7).
__global__ __launch_bounds__(256, 4) void mlp_kernel(
    const float* __restrict__ data, const float* __restrict__ feats,
    const float* __restrict__ patch, const int* __restrict__ leaf_idx,
    const short* __restrict__ bph, const short* __restrict__ bpl,
    const float* __restrict__ hf_b1, const float* __restrict__ hf_w2,
    const float* __restrict__ hf_b2,
    const float* __restrict__ hs_b1, const float* __restrict__ hs_w2,
    const float* __restrict__ hs_b2,
    float* __restrict__ out, int L)
{
    int lane = threadIdx.x & 63;
    int base = blockIdx.x * 256 + (threadIdx.x >> 6) * 64;
    if (base >= L) return;
    int n0 = lane & 15;
    int kg = lane >> 4;
    int k0 = kg * 8;

    float fts[8];
    #pragma unroll
    for (int i = 0; i < 8; ++i) fts[i] = feats[k0 + i];

    float w2r[16], b1r[8];
    #pragma unroll
    for (int t = 0; t < 4; ++t) {
        int h = t * 16 + n0;
        w2r[t * 4 + 0] = hf_w2[h * 3 + 0];
        w2r[t * 4 + 1] = hf_w2[h * 3 + 1];
        w2r[t * 4 + 2] = hf_w2[h * 3 + 2];
        w2r[t * 4 + 3] = hs_w2[h];
        b1r[t]     = hf_b1[h];
        b1r[4 + t] = hs_b1[h];
    }
    float b20 = hf_b2[0], b21 = hf_b2[1], b22 = hf_b2[2], b23 = hs_b2[0];

    #pragma unroll
    for (int tm = 0; tm < 4; ++tm) {
        int r  = base + tm * 16 + n0;
        int rc = r < L ? r : L - 1;
        int row = leaf_idx[rc];
        const float* __restrict__ src = (row == 0) ? patch : (data + (size_t)row * 32);
        float4 v0 = *(const float4*)(src + k0);
        float4 v1 = *(const float4*)(src + k0 + 4);
        float xv[8] = {v0.x, v0.y, v0.z, v0.w, v1.x, v1.y, v1.z, v1.w};
        short8 ahi, alo;
        #pragma unroll
        for (int i = 0; i < 8; ++i) {
            float x = xv[i] + fts[i];
            unsigned short hh = f2bf_rne(x);
            ahi[i] = (short)hh;
            alo[i] = (short)f2bf_rne(x - bf2f(hh));
        }

        f32x4 acc[8];
        #pragma unroll
        for (int q = 0; q < 8; ++q) {
            short8 bh = *(const short8*)(bph + (q * 64 + lane) * 8);
            short8 bl = *(const short8*)(bpl + (q * 64 + lane) * 8);
            f32x4 a = (f32x4){0.f, 0.f, 0.f, 0.f};
            a = __builtin_amdgcn_mfma_f32_16x16x32_bf16(ahi, bh, a, 0, 0, 0);
            a = __builtin_amdgcn_mfma_f32_16x16x32_bf16(alo, bh, a, 0, 0, 0);
            a = __builtin_amdgcn_mfma_f32_16x16x32_bf16(ahi, bl, a, 0, 0, 0);
            acc[q] = a;
        }

        float o[4][4];
        #pragma unroll
        for (int g2 = 0; g2 < 4; ++g2) {
            #pragma unroll
            for (int c = 0; c < 4; ++c) o[g2][c] = 0.f;
        }
        #pragma unroll
        for (int t = 0; t < 4; ++t) {
            #pragma unroll
            for (int reg = 0; reg < 4; ++reg) {
                float gf = gelu_erf(acc[t][reg] + b1r[t]);
                float gs = gelu_erf(acc[4 + t][reg] + b1r[4 + t]);
                o[reg][0] = fmaf(gf, w2r[t * 4 + 0], o[reg][0]);
                o[reg][1] = fmaf(gf, w2r[t * 4 + 1], o[reg][1]);
                o[reg][2] = fmaf(gf, w2r[t * 4 + 2], o[reg][2]);
                o[reg][3] = fmaf(gs, w2r[t * 4 + 3], o[reg][3]);
            }
        }
        #pragma unroll
        for (int mk = 1; mk < 16; mk <<= 1) {
            #pragma unroll
            for (int reg = 0; reg < 4; ++reg) {
                #pragma unroll
                for (int c = 0; c < 4; ++c)
                    o[reg][c] += __shfl_xor(o[reg][c], mk, 64);
            }
        }
        if (n0 < 4) {
            int rL = base + tm * 16 + kg * 4 + n0;
            if (rL < L) {
                float s0 = n0 == 0 ? o[0][0] : n0 == 1 ? o[1][0] : n0 == 2 ? o[2][0] : o[3][0];
                float s1 = n0 == 0 ? o[0][1] : n0 == 1 ? o[1][1] : n0 == 2 ? o[2][1] : o[3][1];
                float s2 = n0 == 0 ? o[0][2] : n0 == 1 ? o[1][2] : n0 == 2 ? o[2][2] : o[3][2];
                float s3 = n0 == 0 ? o[0][3] : n0 == 1 ? o[1][3] : n0 == 2 ? o[2][3] : o[3][3];
                float4 res = {s0 + b20, s1 + b21, s2 + b22, s3 + b23};
                *(float4*)(out + (size_t)rL * 4) = res;
            }
        }
    }
}

extern "C" void kernel_launch(void* const* d_in, const int* in_sizes, int n_in,
                              void* d_out, int out_size, void* d_ws, size_t ws_size,
                              hipStream_t stream)
{
    const float* data         = (const float*)d_in[0];
    const float* conv_w       = (const float*)d_in[1];
    const float* conv_b       = (const float*)d_in[2];
    const float* depth_weight = (const float*)d_in[3];
    const float* hf_w1        = (const float*)d_in[4];
    const float* hf_b1        = (const float*)d_in[5];
    const float* hf_w2        = (const float*)d_in[6];
    const float* hf_b2        = (const float*)d_in[7];
    const float* hs_w1        = (const float*)d_in[8];
    const float* hs_b1        = (const float*)d_in[9];
    const float* hs_w2        = (const float*)d_in[10];
    const float* hs_b2        = (const float*)d_in[11];
    const int*   idx_sorted   = (const int*)d_in[12];
    const int*   depth_sorted = (const int*)d_in[13];
    const int*   node_depth   = (const int*)d_in[14];
    const int*   leaf_idx     = (const int*)d_in[15];

    int M = in_sizes[12];   // 30000
    int L = in_sizes[15];   // 210001
    float* out = (float*)d_out;

    // ws layout (floats): Wt[81920] | feats[32] | patch[32] | pfeats[M*32]
    //   | bph[4096 sh] | bpl[4096 sh] | gcnt[10*RSTRIDE ints] | runlist[10*RCAP int2]
    float* Wt      = (float*)d_ws;
    float* feats   = Wt + WT_N;
    float* patch   = feats + 32;
    float* pfeats  = patch + 32;
    short* bph     = (short*)(pfeats + (size_t)M * 32);
    short* bpl     = bph + 4096;
    int*   gcnt    = (int*)(bpl + 4096);
    int2*  runlist = (int2*)(gcnt + 10 * RSTRIDE);

    hipMemsetAsync(gcnt, 0, 10 * RSTRIDE * sizeof(int), stream);

    int prep_total = M + WT_N + 32 + 512;
    prep_kernel<<<(prep_total + 255) / 256, 256, 0, stream>>>(
        conv_w, Wt, feats, hf_w1, hs_w1, bph, bpl,
        idx_sorted, node_depth, gcnt, runlist, M);

    // wave per run entry; total runs <= M, extra waves exit after prefix read
    conv_scan<<<(M + 3) / 4, 256, 0, stream>>>(data, Wt, conv_b, depth_weight,
                                               idx_sorted, depth_sorted,
                                               gcnt, runlist,
                                               pfeats, patch, M);

    reduce_feats<<<(M + 999) / 1000, 1024, 0, stream>>>(idx_sorted, pfeats, feats, M);

    mlp_kernel<<<(L + 255) / 256, 256, 0, stream>>>(data, feats, patch, leaf_idx,
                                                    bph, bpl,
                                                    hf_b1, hf_w2, hf_b2,
                                                    hs_b1, hs_w2, hs_b2,
                                                    out, L);
}